// Round 5
// baseline (77.370 us; speedup 1.0000x reference)
//
#include <hip/hip_runtime.h>

// ChamferLoss: B=4, N=M=8192, D=3, fp32. Scalar out.
// MFMA split-f16 (validated EXACT r6-r20): A = refs (LDS), B = queries (regs),
// in-lane min3 tree, VGPR-dest asm MFMA (r13).
// LEDGER: r0(2+2 asm, 8-wave band)=77.4 | r17 fused-reduce fence=149 (NEVER
// per-block agent fences) | r18 presplit=80.1 | r19 presplit+gload_lds=82.8
// (extra dispatches cost more than hidden prologue VALU saves) | r20 4-fused
// MFMA @ 4-wave band=75.5 (WIN -1.9us).
// r21 (this): rotated 2+2 software pipeline. r20's chain was serial per wave
// (ds_read wait -> 4 issue -> 16 nops -> 4 trees) in 4-wave lockstep ->
// ~38% per-wave MFMA duty. Rotate trees between issue groups:
//   tree(d01,mt-1) -> issue(d01,mt) -> tree(d23,mt-1) -> issue(d23,mt)
// Every MFMA->dst-read distance ~40-55cyc > r15's validated ~34cyc margin ->
// ZERO s_nops in steady state; prologue/tail keep 2x s_nop7. Per-wave tile
// offset (wave*4, min is order-invariant) breaks the initial convoy; pipe
// backpressure keeps waves desynced. d-pairs retire before reissue: ~110
// VGPR, still 4-wave band, __launch_bounds__(256,4).
// Guards: absmax!=0 => hazard margin violated -> revert r20 + s_nops.
//         FETCH/WRITE jump on mfma dispatch => spill -> revert.

#define BATCH   4
#define NPTS    8192
#define TPB     256
#define CSLICE  512                  // ref points per block (LDS slice)
#define QT      4                    // query tiles (32 cols) per wave
#define QBLK    (4 * QT * 32)        // 512 queries per block
#define MT      (CSLICE / 32)        // 16 ref tiles per slice
#define SLICES  (NPTS / CSLICE)      // 16
#define QBLKS   (NPTS / QBLK)        // 16

typedef _Float16 h8   __attribute__((ext_vector_type(8)));
typedef float    f16v __attribute__((ext_vector_type(16)));

__device__ __forceinline__ void split16(float v, _Float16& hi, _Float16& lo) {
    hi = (_Float16)v;
    lo = (_Float16)(v - (float)hi);
}

__device__ __forceinline__ float tree16(const f16v& d) {
    float g0 = fminf(fminf(d[0],  d[1]),  d[2]);
    float g1 = fminf(fminf(d[3],  d[4]),  d[5]);
    float g2 = fminf(fminf(d[6],  d[7]),  d[8]);
    float g3 = fminf(fminf(d[9],  d[10]), d[11]);
    float g4 = fminf(fminf(d[12], d[13]), d[14]);
    float h0 = fminf(fminf(g0, g1), d[15]);
    float h1 = fminf(fminf(g2, g3), g4);
    return fminf(h0, h1);
}

__global__ __launch_bounds__(TPB, 4) void chamfer_mfma(const float* __restrict__ xg,
                                                       const float* __restrict__ yg,
                                                       float* __restrict__ partial,
                                                       float* __restrict__ out) {
    __shared__ h8 afrag[CSLICE * 2];          // 16 KB, de-interleaved (conflict-free)

    const int tid    = threadIdx.x;
    const int qblock = blockIdx.x;            // [0,16)
    const int slice  = blockIdx.y & (SLICES - 1);
    const int b      = blockIdx.y >> 4;       // SLICES == 16
    const int dir    = blockIdx.z;
    const int lane   = tid & 63, wave = tid >> 6;
    const int col    = lane & 31, hv = lane >> 5;

    if (tid == 0) out[0] = 0.0f;              // benign identical-value race;
                                              // reduce runs after via stream order
    const float* q = dir ? yg : xg;           // query side (cols, register B-frags)
    const float* r = dir ? xg : yg;           // reference side (rows, LDS A-frags)

    // ---- stage ref A-frags: 2 points per thread, de-interleaved layout ----
    const float* rbase = r + ((size_t)b * NPTS + slice * CSLICE) * 3;
#pragma unroll
    for (int i = 0; i < CSLICE / TPB; ++i) {
        const int p = tid + i * TPB;
        float r0 = rbase[p * 3 + 0], r1 = rbase[p * 3 + 1], r2 = rbase[p * 3 + 2];
        _Float16 h0, l0, h1, l1, h2, l2, rnh, rnl;
        split16(r0, h0, l0);                  // a-side: RAW coords
        split16(r1, h1, l1);
        split16(r2, h2, l2);
        split16(fmaf(r0, r0, fmaf(r1, r1, r2 * r2)), rnh, rnl);
        const int base = (p >> 5) * 64 + (p & 31);            // [tile][hv][row]
        afrag[base]      = (h8){h0, h1, h2, l0, l1, l2, h0, h1};            // k0..7
        afrag[base + 32] = (h8){h2, rnh, rnl, (_Float16)1.0f, (_Float16)1.0f,
                                (_Float16)0.0f, (_Float16)0.0f, (_Float16)0.0f}; // k8..15
    }

    // ---- query B-frags: QT col-tiles per wave, resident in registers ----
    h8 bq[QT];
#pragma unroll
    for (int t = 0; t < QT; ++t) {
        const int qi = qblock * QBLK + (wave * QT + t) * 32 + col;
        const float* qp = q + ((size_t)b * NPTS + qi) * 3;
        float x0 = qp[0], x1 = qp[1], x2 = qp[2];
        _Float16 H0, L0, H1, L1, H2, L2, qnh, qnl;
        split16(-2.0f * x0, H0, L0);          // b-side: -2q, split AFTER scaling
        split16(-2.0f * x1, H1, L1);
        split16(-2.0f * x2, H2, L2);
        split16(fmaf(x0, x0, fmaf(x1, x1, x2 * x2)), qnh, qnl);
        h8 b0 = {H0, H1, H2, H0, H1, H2, L0, L1};                           // k0..7
        h8 b1 = {L2, (_Float16)1.0f, (_Float16)1.0f, qnh, qnl,
                 (_Float16)0.0f, (_Float16)0.0f, (_Float16)0.0f};           // k8..15
        bq[t] = hv ? b1 : b0;
    }
    __syncthreads();

    float cm[QT];
#pragma unroll
    for (int t = 0; t < QT; ++t) cm[t] = 3.0e38f;

    const int mtb = wave * 4;                 // per-wave tile offset (convoy breaker)

    // ---- rotated 2+2 software pipeline ----
    // prologue: tile 0 issued with the r15-validated nop tail
    f16v d0, d1, d2, d3;
    {
        const h8 ar = afrag[(mtb & 15) * 64 + lane];
        asm("v_mfma_f32_32x32x16_f16 %0, %2, %3, 0\n\t"
            "v_mfma_f32_32x32x16_f16 %1, %2, %4, 0"
            : "=v"(d0), "=v"(d1)
            : "v"(ar), "v"(bq[0]), "v"(bq[1]));
        asm("v_mfma_f32_32x32x16_f16 %0, %2, %3, 0\n\t"
            "v_mfma_f32_32x32x16_f16 %1, %2, %4, 0\n\t"
            "s_nop 7\n\t"
            "s_nop 7"
            : "=v"(d2), "=v"(d3)
            : "v"(ar), "v"(bq[2]), "v"(bq[3]));
    }
    // steady state: tree(pair, mt-1) in the issue shadow of the other pair
    for (int mt = 1; mt < MT; ++mt) {
        const h8 ar = afrag[(((mt + mtb) & 15)) * 64 + lane];
        cm[0] = fminf(cm[0], tree16(d0));     // d0,d1 issued >=40cyc ago
        cm[1] = fminf(cm[1], tree16(d1));
        asm("v_mfma_f32_32x32x16_f16 %0, %2, %3, 0\n\t"
            "v_mfma_f32_32x32x16_f16 %1, %2, %4, 0"
            : "=v"(d0), "=v"(d1)
            : "v"(ar), "v"(bq[0]), "v"(bq[1]));
        cm[2] = fminf(cm[2], tree16(d2));     // d2,d3 issued >=40cyc ago
        cm[3] = fminf(cm[3], tree16(d3));
        asm("v_mfma_f32_32x32x16_f16 %0, %2, %3, 0\n\t"
            "v_mfma_f32_32x32x16_f16 %1, %2, %4, 0"
            : "=v"(d2), "=v"(d3)
            : "v"(ar), "v"(bq[2]), "v"(bq[3]));
    }
    // tail: drain last tile with explicit hazard margin
    asm volatile("s_nop 7\n\ts_nop 7" ::: "memory");
    cm[0] = fminf(cm[0], tree16(d0));
    cm[1] = fminf(cm[1], tree16(d1));
    cm[2] = fminf(cm[2], tree16(d2));
    cm[3] = fminf(cm[3], tree16(d3));

    // ---- epilogue: one xor32 per accumulator, coalesced stores ----
    float* pp = partial + ((size_t)(dir * BATCH + b) * SLICES + slice) * NPTS
                        + qblock * QBLK;
#pragma unroll
    for (int t = 0; t < QT; ++t) {
        cm[t] = fminf(cm[t], __shfl_xor(cm[t], 32, 64));   // hv-partner rows
        if (hv == 0)
            pp[(wave * QT + t) * 32 + col] = cm[t];        // 32 lanes, 128B coalesced
    }
}

__global__ __launch_bounds__(TPB) void chamfer_reduce(const float* __restrict__ partial,
                                                      float* __restrict__ out) {
    const int tid = threadIdx.x;
    const int g   = blockIdx.x * TPB + tid;   // [0, 2*BATCH*NPTS)
    const int db  = g >> 13;                  // (dir*BATCH + b)
    const int n   = g & (NPTS - 1);

    const float* p = partial + (size_t)db * SLICES * NPTS + n;
    float v = 3.0e38f;
#pragma unroll
    for (int s = 0; s < SLICES; ++s)
        v = fminf(v, p[(size_t)s * NPTS]);    // coalesced across threads

    float w = v;
#pragma unroll
    for (int off = 32; off > 0; off >>= 1)
        w += __shfl_down(w, off, 64);
    __shared__ float ss[TPB / 64];
    if ((tid & 63) == 0) ss[tid >> 6] = w;
    __syncthreads();
    if (tid == 0)
        atomicAdd(out, (ss[0] + ss[1] + ss[2] + ss[3]) * (1.0f / (float)(BATCH * NPTS)));
}

extern "C" void kernel_launch(void* const* d_in, const int* in_sizes, int n_in,
                              void* d_out, int out_size, void* d_ws, size_t ws_size,
                              hipStream_t stream) {
    const float* x = (const float*)d_in[0];
    const float* y = (const float*)d_in[1];
    float* out = (float*)d_out;
    float* partial = (float*)d_ws;            // 2*4*16*8192*4 = 4 MB

    chamfer_mfma<<<dim3(QBLKS, BATCH * SLICES, 2), TPB, 0, stream>>>(x, y, partial, out);
    chamfer_reduce<<<dim3(2 * BATCH * NPTS / TPB), TPB, 0, stream>>>(partial, out);
}